// Round 11
// baseline (28.031 us; speedup 1.0000x reference)
//
#include <hip/hip_runtime.h>

#define NA 32768
#define RR 168                    // per-wave region row stride (ush): 336 B, 16B-aligned, bank-friendly
#define TAB 17408                 // staged tables in ush: gw1 frags 8192 + W2p frags 9216

typedef float  f32x4  __attribute__((ext_vector_type(4)));
typedef __bf16 bf16x8 __attribute__((ext_vector_type(8)));
typedef unsigned short u16x8 __attribute__((ext_vector_type(8)));
typedef unsigned short u16x4 __attribute__((ext_vector_type(4)));

// ws layout (unsigned short offsets):
//   [0,8192)      fragB_gw1  [ct4][kt4][lane64][8]
//   [8192,17408)  fragB_w2p  [ct9][kt2][lane64][8]   (wpost+scale folded)
//   [17408,19456) fragB_w0   [kt4][lane64][8]        (x 1/sqrt(128))
//   [19456,20480) fragB_w1   [kt2][lane64][8]        (x 1/sqrt(64))
//   [20480,20992) fragB_w2   [kt1][lane64][8]        (x 1/sqrt(32))
//   byte 41984:   b2p[144] fp32

__device__ __forceinline__ unsigned short bf16u(float f) {
    unsigned int x = __float_as_uint(f);
    x += 0x7FFFu + ((x >> 16) & 1u);          // round-to-nearest-even
    return (unsigned short)(x >> 16);
}
__device__ __forceinline__ unsigned short cvt1(float f) {
    return __builtin_bit_cast(unsigned short, (__bf16)f);
}
__device__ __forceinline__ f32x4 MFMA16(u16x8 a, u16x8 b, f32x4 c) {
    return __builtin_amdgcn_mfma_f32_16x16x32_bf16(
        __builtin_bit_cast(bf16x8, a), __builtin_bit_cast(bf16x8, b), c, 0, 0, 0);
}

__global__ void setup_kernel(const float* __restrict__ gw1,
                             const float* __restrict__ gw2, const float* __restrict__ gb2,
                             const float* __restrict__ w_pre0, const float* __restrict__ w_pre1,
                             const float* __restrict__ w_pre2,
                             const float* __restrict__ wpost0, const float* __restrict__ wpost1,
                             const float* __restrict__ wpost2,
                             unsigned short* __restrict__ wsS, float* __restrict__ b2p)
{
    const int t = blockIdx.x * 256 + threadIdx.x;
    const int LO[9]  = {0,2,0,1,2,2,0,1,2};
    const int POS[9] = {0,0,1,0,1,2,2,1,3};
    const float SCALE[3] = {0.036084391824351615f,   // 1/(4*sqrt(48))
                            0.04419417382415922f,    // 1/(4*sqrt(32))
                            0.03125f};               // 1/(4*sqrt(64))
    if (t < 8192) {                      // gw1 B-frags
        const int j = t & 7, lane = (t >> 3) & 63, kt = (t >> 9) & 3, ct = t >> 11;
        const int k = kt * 32 + ((lane >> 4) & 3) * 8 + j;
        const int n = ct * 16 + (lane & 15);
        wsS[t] = bf16u(gw1[k * 64 + n]);
    } else if (t < 17408) {              // W2p B-frags (fold wpost+scale)
        const int q = t - 8192;
        const int j = q & 7, lane = (q >> 3) & 63, kt = (q >> 9) & 1, ct = q >> 10;
        const int k = kt * 32 + ((lane >> 4) & 3) * 8 + j;
        const int idx = ct, u = lane & 15;
        const int lo = LO[idx];
        const float* wp = (lo == 0) ? wpost0 : (lo == 1) ? wpost1 : wpost2;
        const float* wv = wp + POS[idx] * 16;
        const float* gsrc = gw2 + (size_t)k * 2304 + idx * 256 + u * 16;
        float s = 0.f;
        for (int w = 0; w < 16; ++w) s = fmaf(gsrc[w], wv[w], s);
        wsS[8192 + q] = bf16u(s * SCALE[lo]);
    } else if (t < 19456) {              // w_pre0 B-frags
        const int q = t - 17408;
        const int j = q & 7, lane = (q >> 3) & 63, kt = q >> 9;
        const int k = kt * 32 + ((lane >> 4) & 3) * 8 + j;
        wsS[17408 + q] = bf16u(w_pre0[k * 16 + (lane & 15)] * 0.08838834764831845f);
    } else if (t < 20480) {              // w_pre1 B-frags
        const int q = t - 19456;
        const int j = q & 7, lane = (q >> 3) & 63, kt = q >> 9;
        const int k = kt * 32 + ((lane >> 4) & 3) * 8 + j;
        wsS[19456 + q] = bf16u(w_pre1[k * 16 + (lane & 15)] * 0.125f);
    } else if (t < 20992) {              // w_pre2 B-frags
        const int q = t - 20480;
        const int j = q & 7, lane = (q >> 3) & 63;
        const int k = ((lane >> 4) & 3) * 8 + j;
        wsS[20480 + q] = bf16u(w_pre2[k * 16 + (lane & 15)] * 0.17677669529663687f);
    } else if (t < 21136) {              // b2p (fp32)
        const int e = t - 20992;
        const int idx = e >> 4, u = e & 15;
        const int lo = LO[idx];
        const float* wp = (lo == 0) ? wpost0 : (lo == 1) ? wpost1 : wpost2;
        const float* wv = wp + POS[idx] * 16;
        const float* bsrc = gb2 + idx * 256 + u * 16;
        float sb = 0.f;
        for (int w = 0; w < 16; ++w) sb = fmaf(bsrc[w], wv[w], sb);
        b2p[e] = sb * SCALE[lo];
    }
}

// ---------------------------------------------------------------------------
// One wave = 16 atoms, 4 waves/block (64 atoms/block, 512 blocks).
// gw1+W2p frag tables staged block-wide into LDS (one coalesced burst,
// one __syncthreads), so phases A/B read B-frags via conflict-free
// ds_read_b128 instead of per-wave cross-XCD dirty-line global loads.
// Per-wave reused region [16][RR] for l0/l1a/l1b/l2/Xs/sH; w_pre/b2p
// hoisted to registers at kernel start.
// LDS: 17408 + 4*16*168 = 28160 ush = 56,320 B/block.
// ---------------------------------------------------------------------------
__global__ __launch_bounds__(256) void csc_kernel(
    const float* __restrict__ x_scalar, const float* __restrict__ x_sph,
    const float* __restrict__ gb1,
    const unsigned short* __restrict__ wsS, const float* __restrict__ b2p,
    float* __restrict__ out)
{
    __shared__ __align__(16) unsigned short all[TAB + 4 * 16 * RR];

    const int tid  = threadIdx.x;
    const int lane = tid & 63;
    const int wvi  = tid >> 6;
    const int lm = lane & 15, lg = lane >> 4;
    const int n0 = (blockIdx.x * 4 + wvi) * 16;
    unsigned short* __restrict__ sTab = all;
    unsigned short* __restrict__ Bw   = all + TAB + wvi * 16 * RR;

    // ---- stage weight tables to LDS (coalesced 16B units; 2176 units) ----
    {
        u16x8 t[9];
#pragma unroll
        for (int i = 0; i < 9; ++i) {
            const int off = i * 256 + tid;
            t[i] = (off < 2176) ? *(const u16x8*)(wsS + (size_t)off * 8)
                                : (u16x8){0,0,0,0,0,0,0,0};
        }
#pragma unroll
        for (int i = 0; i < 9; ++i) {
            const int off = i * 256 + tid;
            if (off < 2176) *(u16x8*)&sTab[(size_t)off * 8] = t[i];
        }
    }

    // ---- early register loads: w_pre frags, b2p, gb1 ----
    u16x8 w0f[4], w1f[2], w2f;
#pragma unroll
    for (int kt = 0; kt < 4; ++kt) w0f[kt] = *(const u16x8*)(wsS + 17408 + (size_t)(kt*64+lane)*8);
#pragma unroll
    for (int kt = 0; kt < 2; ++kt) w1f[kt] = *(const u16x8*)(wsS + 19456 + (size_t)(kt*64+lane)*8);
    w2f = *(const u16x8*)(wsS + 20480 + (size_t)lane*8);
    float bini[7];
    {
        const int CTs[7] = {0,1,2,4,5,6,8};
#pragma unroll
        for (int c = 0; c < 7; ++c) bini[c] = b2p[CTs[c]*16 + lm];
    }
    const float gb0 = gb1[lm], gbq1 = gb1[16+lm], gbq2 = gb1[32+lm], gbq3 = gb1[48+lm];

    __syncthreads();   // publish sTab (only block-wide sync in the kernel)

    const float* __restrict__ srcq = x_sph + (size_t)n0 * 480;

    // ================= phase l0: x_sph cols [0,128) =================
    {
        float4 v[8];
#pragma unroll
        for (int i = 0; i < 8; ++i) {
            const int idx4 = i * 64 + lane;
            v[i] = *(const float4*)(srcq + (size_t)(idx4 >> 5) * 480 + (idx4 & 31) * 4);
        }
#pragma unroll
        for (int i = 0; i < 8; ++i) {
            const int idx4 = i * 64 + lane;
            const int row = idx4 >> 5, c4 = idx4 & 31;
            const u16x4 w = { cvt1(v[i].x), cvt1(v[i].y), cvt1(v[i].z), cvt1(v[i].w) };
            *(u16x4*)&Bw[row * RR + c4 * 4] = w;
        }
    }
    f32x4 acc0 = (f32x4){0.f,0.f,0.f,0.f};
#pragma unroll
    for (int kt = 0; kt < 4; ++kt) {
        const u16x8 f = *(const u16x8*)&Bw[lm * RR + kt * 32 + lg * 8];
        acc0 = MFMA16(f, w0f[kt], acc0);
    }

    // ================= phase l1: cols [128,320) in two 96-col halves =======
    u16x8 f1[3][2];
#pragma unroll
    for (int sub = 0; sub < 2; ++sub) {
        float4 v[6];
#pragma unroll
        for (int i = 0; i < 6; ++i) {
            const int idx4 = i * 64 + lane;
            const int row = idx4 / 24, c4 = idx4 - row * 24;
            v[i] = *(const float4*)(srcq + (size_t)row * 480 + 128 + sub * 96 + c4 * 4);
        }
#pragma unroll
        for (int i = 0; i < 6; ++i) {
            const int idx4 = i * 64 + lane;
            const int row = idx4 / 24, c4 = idx4 - row * 24;
            const u16x4 w = { cvt1(v[i].x), cvt1(v[i].y), cvt1(v[i].z), cvt1(v[i].w) };
            *(u16x4*)&Bw[row * RR + c4 * 4] = w;
        }
        const int base = lm * RR + 24 * lg;
        const u16x8 sA = *(const u16x8*)&Bw[base];
        const u16x8 sB = *(const u16x8*)&Bw[base + 8];
        const u16x8 sC = *(const u16x8*)&Bw[base + 16];
        unsigned short span[24];
#pragma unroll
        for (int e = 0; e < 8; ++e) { span[e] = sA[e]; span[8+e] = sB[e]; span[16+e] = sC[e]; }
#pragma unroll
        for (int m = 0; m < 3; ++m) {
            u16x8 f;
#pragma unroll
            for (int j = 0; j < 8; ++j) f[j] = span[3 * j + m];
            f1[m][sub] = f;
        }
    }
    f32x4 accP[3];
#pragma unroll
    for (int m = 0; m < 3; ++m) {
        f32x4 a = (f32x4){0.f,0.f,0.f,0.f};
        a = MFMA16(f1[m][0], w1f[0], a);
        a = MFMA16(f1[m][1], w1f[1], a);
        accP[m] = a;
    }

    // ================= phase l2: cols [320,480) =================
    {
        float4 v[10];
#pragma unroll
        for (int i = 0; i < 10; ++i) {
            const int idx4 = i * 64 + lane;
            const int row = idx4 / 40, c4 = idx4 - row * 40;
            v[i] = *(const float4*)(srcq + (size_t)row * 480 + 320 + c4 * 4);
        }
#pragma unroll
        for (int i = 0; i < 10; ++i) {
            const int idx4 = i * 64 + lane;
            const int row = idx4 / 40, c4 = idx4 - row * 40;
            const u16x4 w = { cvt1(v[i].x), cvt1(v[i].y), cvt1(v[i].z), cvt1(v[i].w) };
            *(u16x4*)&Bw[row * RR + c4 * 4] = w;
        }
    }
    f32x4 accQ[5];
    {
        unsigned short span[40];
        const int base = lm * RR + 40 * lg;
#pragma unroll
        for (int c = 0; c < 5; ++c) {
            const u16x8 s = *(const u16x8*)&Bw[base + c * 8];
#pragma unroll
            for (int e = 0; e < 8; ++e) span[c * 8 + e] = s[e];
        }
#pragma unroll
        for (int m = 0; m < 5; ++m) {
            u16x8 f;
#pragma unroll
            for (int j = 0; j < 8; ++j) f[j] = span[5 * j + m];
            accQ[m] = MFMA16(f, w2f, (f32x4){0.f,0.f,0.f,0.f});
        }
    }

    // ================= phase Xs + A: H = silu(Xs @ gw1 + gb1) ==============
    {
        const float* __restrict__ src = x_scalar + (size_t)n0 * 128;
        float4 v[8];
#pragma unroll
        for (int i = 0; i < 8; ++i) v[i] = *(const float4*)(src + (size_t)(i * 64 + lane) * 4);
#pragma unroll
        for (int i = 0; i < 8; ++i) {
            const int idx4 = i * 64 + lane;
            const int row = idx4 >> 5, c4 = idx4 & 31;
            const u16x4 w = { cvt1(v[i].x), cvt1(v[i].y), cvt1(v[i].z), cvt1(v[i].w) };
            *(u16x4*)&Bw[row * RR + c4 * 4] = w;
        }
    }
    f32x4 accA0 = (f32x4){gb0,gb0,gb0,gb0};
    f32x4 accA1 = (f32x4){gbq1,gbq1,gbq1,gbq1};
    f32x4 accA2 = (f32x4){gbq2,gbq2,gbq2,gbq2};
    f32x4 accA3 = (f32x4){gbq3,gbq3,gbq3,gbq3};
    u16x8 af[4];
#pragma unroll
    for (int kt = 0; kt < 4; ++kt) af[kt] = *(const u16x8*)&Bw[lm * RR + kt * 32 + lg * 8];
#pragma unroll
    for (int kt = 0; kt < 4; ++kt) {
        accA0 = MFMA16(af[kt], *(const u16x8*)&sTab[(size_t)((0*4+kt)*64+lane)*8], accA0);
        accA1 = MFMA16(af[kt], *(const u16x8*)&sTab[(size_t)((1*4+kt)*64+lane)*8], accA1);
        accA2 = MFMA16(af[kt], *(const u16x8*)&sTab[(size_t)((2*4+kt)*64+lane)*8], accA2);
        accA3 = MFMA16(af[kt], *(const u16x8*)&sTab[(size_t)((3*4+kt)*64+lane)*8], accA3);
    }
    // silu -> sH stored in-place in Bw (Xs data dead after af reads; in-wave DS order)
#pragma unroll
    for (int r = 0; r < 4; ++r) {
        const int atom = lg * 4 + r;
        const float v0 = accA0[r], v1 = accA1[r], v2 = accA2[r], v3 = accA3[r];
        Bw[atom * RR +  0 + lm] = cvt1(v0 / (1.f + __expf(-v0)));
        Bw[atom * RR + 16 + lm] = cvt1(v1 / (1.f + __expf(-v1)));
        Bw[atom * RR + 32 + lm] = cvt1(v2 / (1.f + __expf(-v2)));
        Bw[atom * RR + 48 + lm] = cvt1(v3 / (1.f + __expf(-v3)));
    }

    // ================= phase B: G = b2p + H @ W2p =================
    const u16x8 hf0 = *(const u16x8*)&Bw[lm * RR + lg * 8];
    const u16x8 hf1 = *(const u16x8*)&Bw[lm * RR + 32 + lg * 8];
    f32x4 gB0, gB1, gB2, gB4, gB5, gB6, gB8;
    gB0 = (f32x4){bini[0],bini[0],bini[0],bini[0]};
    gB1 = (f32x4){bini[1],bini[1],bini[1],bini[1]};
    gB2 = (f32x4){bini[2],bini[2],bini[2],bini[2]};
    gB4 = (f32x4){bini[3],bini[3],bini[3],bini[3]};
    gB5 = (f32x4){bini[4],bini[4],bini[4],bini[4]};
    gB6 = (f32x4){bini[5],bini[5],bini[5],bini[5]};
    gB8 = (f32x4){bini[6],bini[6],bini[6],bini[6]};
#define DOB(ACC, CT) \
    ACC = MFMA16(hf0, *(const u16x8*)&sTab[8192 + (size_t)(((CT)*2+0)*64+lane)*8], ACC); \
    ACC = MFMA16(hf1, *(const u16x8*)&sTab[8192 + (size_t)(((CT)*2+1)*64+lane)*8], ACC);
    DOB(gB0,0) DOB(gB1,1) DOB(gB2,2) DOB(gB4,4) DOB(gB5,5) DOB(gB6,6) DOB(gB8,8)

    // ================= TP epilogue =================
    const float C110 = 0.5773502691896258f;
    const float C220 = 0.4472135954999579f;
    const float Ca = 0.31622776601683794f, Cb = 0.18257418583505536f;
    const float A2 = 0.2390457218668787f, B2c = 0.20701966780270626f, D2 = 0.11952286093343936f;
    const float is3 = 0.5773502691896258f, is6 = 0.4082482904638631f, is2 = 0.7071067811865476f;

#pragma unroll
    for (int r = 0; r < 4; ++r) {
        const int row = lg * 4 + r;
        const float h0 = acc0[r];
        const float p0 = accP[0][r], p1 = accP[1][r], p2 = accP[2][r];
        const float q0 = accQ[0][r], q1 = accQ[1][r], q2 = accQ[2][r],
                    q3 = accQ[3][r], q4 = accQ[4][r];
        const float G0 = gB0[r], G1 = gB1[r], G2 = gB2[r], G4 = gB4[r],
                    G5 = gB5[r], G6 = gB6[r], G8 = gB8[r];

        float y0 = G0 * h0 * h0
                 + G2 * C110 * (p0*p0 + p1*p1 + p2*p2)
                 + G6 * C220 * (q0*q0 + q1*q1 + q2*q2 + q3*q3 + q4*q4);
        float z0, z1, z2, z3, z4;
        {
            const float c15 = C220 * h0 * (G1 + G5);
            z0 = c15 * q0; z1 = c15 * q1; z2 = c15 * q2; z3 = c15 * q3; z4 = c15 * q4;
        }
        z0 = fmaf(G4, 2.f*Ca*p0*p2, z0);
        z1 = fmaf(G4, 2.f*Ca*p0*p1, z1);
        z2 = fmaf(G4, Cb*(2.f*p1*p1 - p0*p0 - p2*p2), z2);
        z3 = fmaf(G4, 2.f*Ca*p2*p1, z3);
        z4 = fmaf(G4, Ca*(p2*p2 - p0*p0), z4);
        z0 = fmaf(G8, -2.f*A2*q0*q2 + 2.f*B2c*q1*q3, z0);
        z1 = fmaf(G8,  2.f*B2c*(q0*q3 - q4*q1) + 2.f*D2*q1*q2, z1);
        z2 = fmaf(G8,  A2*(q2*q2 - q0*q0 - q4*q4) + D2*(q1*q1 + q3*q3), z2);
        z3 = fmaf(G8,  2.f*B2c*(q0*q1 + q3*q4) + 2.f*D2*q2*q3, z3);
        z4 = fmaf(G8, -2.f*A2*q2*q4 + B2c*(q3*q3 - q1*q1), z4);

#pragma unroll
        for (int msk = 1; msk <= 8; msk <<= 1) {   // reduce over 16 u-lanes
            y0 += __shfl_xor(y0, msk, 64);
            z0 += __shfl_xor(z0, msk, 64);
            z1 += __shfl_xor(z1, msk, 64);
            z2 += __shfl_xor(z2, msk, 64);
            z3 += __shfl_xor(z3, msk, 64);
            z4 += __shfl_xor(z4, msk, 64);
        }

        const float c0 = y0*is3 - z2*is6 - z4*is2;
        const float c4 = y0*is3 + 2.f*z2*is6;
        const float c8 = y0*is3 - z2*is6 + z4*is2;
        const float c1 = z1*is2, c2v = z0*is2, c5 = z3*is2;
        if (lm < 9) {
            const float val = (lm==0)?c8 : (lm==1)?c2v : (lm==2)?c5 : (lm==3)?c2v
                            : (lm==4)?c0 : (lm==5)?c1 : (lm==6)?c5 : (lm==7)?c1 : c4;
            out[(size_t)(n0 + row) * 9 + lm] = val;
        }
    }
}

extern "C" void kernel_launch(void* const* d_in, const int* in_sizes, int n_in,
                              void* d_out, int out_size, void* d_ws, size_t ws_size,
                              hipStream_t stream) {
    const float* x_scalar = (const float*)d_in[0];
    const float* x_sph    = (const float*)d_in[1];
    const float* w_pre0   = (const float*)d_in[2];
    const float* w_pre1   = (const float*)d_in[3];
    const float* w_pre2   = (const float*)d_in[4];
    const float* gw1      = (const float*)d_in[5];
    const float* gb1      = (const float*)d_in[6];
    const float* gw2      = (const float*)d_in[7];
    const float* gb2      = (const float*)d_in[8];
    const float* wpost0   = (const float*)d_in[9];
    const float* wpost1   = (const float*)d_in[10];
    const float* wpost2   = (const float*)d_in[11];

    unsigned short* wsS = (unsigned short*)d_ws;
    float* b2p = (float*)((char*)d_ws + 41984);

    setup_kernel<<<83, 256, 0, stream>>>(gw1, gw2, gb2, w_pre0, w_pre1, w_pre2,
                                         wpost0, wpost1, wpost2, wsS, b2p);
    csc_kernel<<<NA / 64, 256, 0, stream>>>(x_scalar, x_sph, gb1, wsS, b2p, (float*)d_out);
}

// Round 12
// 26.845 us; speedup vs baseline: 1.0442x; 1.0442x over previous
//
#include <hip/hip_runtime.h>

#define NA 32768

typedef float  f32x4  __attribute__((ext_vector_type(4)));
typedef __bf16 bf16x8 __attribute__((ext_vector_type(8)));
typedef unsigned short u16x8 __attribute__((ext_vector_type(8)));
typedef unsigned short u16x4 __attribute__((ext_vector_type(4)));

// ws layout (unsigned short offsets):
//   [0,8192)      fragB_gw1  [ct4][kt4][lane64][8]
//   [8192,17408)  fragB_w2p  [ct9][kt2][lane64][8]   (wpost+scale folded)
//   [17408,19456) fragB_w0   [kt4][lane64][8]        (x 1/sqrt(128))
//   [19456,20480) fragB_w1   [kt2][lane64][8]        (x 1/sqrt(64))
//   [20480,20992) fragB_w2   [kt1][lane64][8]        (x 1/sqrt(32))
//   byte 41984:   b2p[144] fp32

__device__ __forceinline__ unsigned short bf16u(float f) {
    unsigned int x = __float_as_uint(f);
    x += 0x7FFFu + ((x >> 16) & 1u);          // round-to-nearest-even
    return (unsigned short)(x >> 16);
}
__device__ __forceinline__ unsigned short cvt1(float f) {
    return __builtin_bit_cast(unsigned short, (__bf16)f);
}
__device__ __forceinline__ f32x4 MFMA16(u16x8 a, u16x8 b, f32x4 c) {
    return __builtin_amdgcn_mfma_f32_16x16x32_bf16(
        __builtin_bit_cast(bf16x8, a), __builtin_bit_cast(bf16x8, b), c, 0, 0, 0);
}

__global__ void setup_kernel(const float* __restrict__ gw1,
                             const float* __restrict__ gw2, const float* __restrict__ gb2,
                             const float* __restrict__ w_pre0, const float* __restrict__ w_pre1,
                             const float* __restrict__ w_pre2,
                             const float* __restrict__ wpost0, const float* __restrict__ wpost1,
                             const float* __restrict__ wpost2,
                             unsigned short* __restrict__ wsS, float* __restrict__ b2p)
{
    const int t = blockIdx.x * 256 + threadIdx.x;
    const int LO[9]  = {0,2,0,1,2,2,0,1,2};
    const int POS[9] = {0,0,1,0,1,2,2,1,3};
    const float SCALE[3] = {0.036084391824351615f,   // 1/(4*sqrt(48))
                            0.04419417382415922f,    // 1/(4*sqrt(32))
                            0.03125f};               // 1/(4*sqrt(64))
    if (t < 8192) {                      // gw1 B-frags
        const int j = t & 7, lane = (t >> 3) & 63, kt = (t >> 9) & 3, ct = t >> 11;
        const int k = kt * 32 + ((lane >> 4) & 3) * 8 + j;
        const int n = ct * 16 + (lane & 15);
        wsS[t] = bf16u(gw1[k * 64 + n]);
    } else if (t < 17408) {              // W2p B-frags (fold wpost+scale)
        const int q = t - 8192;
        const int j = q & 7, lane = (q >> 3) & 63, kt = (q >> 9) & 1, ct = q >> 10;
        const int k = kt * 32 + ((lane >> 4) & 3) * 8 + j;
        const int idx = ct, u = lane & 15;
        const int lo = LO[idx];
        const float* wp = (lo == 0) ? wpost0 : (lo == 1) ? wpost1 : wpost2;
        const float* wv = wp + POS[idx] * 16;
        const float* gsrc = gw2 + (size_t)k * 2304 + idx * 256 + u * 16;
        float s = 0.f;
        for (int w = 0; w < 16; ++w) s = fmaf(gsrc[w], wv[w], s);
        wsS[8192 + q] = bf16u(s * SCALE[lo]);
    } else if (t < 19456) {              // w_pre0 B-frags
        const int q = t - 17408;
        const int j = q & 7, lane = (q >> 3) & 63, kt = q >> 9;
        const int k = kt * 32 + ((lane >> 4) & 3) * 8 + j;
        wsS[17408 + q] = bf16u(w_pre0[k * 16 + (lane & 15)] * 0.08838834764831845f);
    } else if (t < 20480) {              // w_pre1 B-frags
        const int q = t - 19456;
        const int j = q & 7, lane = (q >> 3) & 63, kt = q >> 9;
        const int k = kt * 32 + ((lane >> 4) & 3) * 8 + j;
        wsS[19456 + q] = bf16u(w_pre1[k * 16 + (lane & 15)] * 0.125f);
    } else if (t < 20992) {              // w_pre2 B-frags
        const int q = t - 20480;
        const int j = q & 7, lane = (q >> 3) & 63;
        const int k = ((lane >> 4) & 3) * 8 + j;
        wsS[20480 + q] = bf16u(w_pre2[k * 16 + (lane & 15)] * 0.17677669529663687f);
    } else if (t < 21136) {              // b2p (fp32)
        const int e = t - 20992;
        const int idx = e >> 4, u = e & 15;
        const int lo = LO[idx];
        const float* wp = (lo == 0) ? wpost0 : (lo == 1) ? wpost1 : wpost2;
        const float* wv = wp + POS[idx] * 16;
        const float* bsrc = gb2 + idx * 256 + u * 16;
        float sb = 0.f;
        for (int w = 0; w < 16; ++w) sb = fmaf(bsrc[w], wv[w], sb);
        b2p[e] = sb * SCALE[lo];
    }
}

// ---------------------------------------------------------------------------
// One wave = 16 atoms, 4 waves/block (64 atoms/block, 512 blocks).
// Per-wave LDS: one REUSED region R[16][200] (l0 -> l1 -> l2 -> Xs phases)
// + sH[16][72]. 4352 ush/wave -> 34,816 B/block.
// Wave-private (no barriers); in-wave lgkm ordering handles region reuse.
// Phase order: l0 C0 | l1 C1 | l2 C2 | Xs A | B | TP.
// ---------------------------------------------------------------------------
#define RR 200
#define SHO 3200

__global__ __launch_bounds__(256, 4) void csc_kernel(
    const float* __restrict__ x_scalar, const float* __restrict__ x_sph,
    const float* __restrict__ gb1,
    const unsigned short* __restrict__ wsS, const float* __restrict__ b2p,
    float* __restrict__ out)
{
    __shared__ __align__(16) unsigned short buf[4][4352];

    const int lane = threadIdx.x & 63;
    const int wvi  = threadIdx.x >> 6;
    const int lm = lane & 15, lg = lane >> 4;
    const int n0 = (blockIdx.x * 4 + wvi) * 16;
    unsigned short* __restrict__ B = buf[wvi];

    const float* __restrict__ srcq = x_sph + (size_t)n0 * 480;

    // ================= phase l0: stage cols [0,128) =================
    {
        float4 v[8];
#pragma unroll
        for (int i = 0; i < 8; ++i) {
            const int idx4 = i * 64 + lane;
            const int row = idx4 >> 5, col4 = idx4 & 31;
            v[i] = *(const float4*)(srcq + (size_t)row * 480 + col4 * 4);
        }
#pragma unroll
        for (int i = 0; i < 8; ++i) {
            const int idx4 = i * 64 + lane;
            const int row = idx4 >> 5, col4 = idx4 & 31;
            const u16x4 w = { cvt1(v[i].x), cvt1(v[i].y), cvt1(v[i].z), cvt1(v[i].w) };
            *(u16x4*)&B[row * RR + col4 * 4] = w;
        }
    }
    f32x4 acc0 = (f32x4){0.f,0.f,0.f,0.f};
#pragma unroll
    for (int kt = 0; kt < 4; ++kt) {
        const u16x8 f = *(const u16x8*)&B[lm * RR + kt * 32 + lg * 8];
        acc0 = MFMA16(f, *(const u16x8*)(wsS + 17408 + (size_t)(kt*64+lane)*8), acc0);
    }

    // ================= phase l1: stage cols [128,320) =================
    {
        float4 v[12];
#pragma unroll
        for (int i = 0; i < 12; ++i) {
            const int idx4 = i * 64 + lane;
            const int row = idx4 / 48, col4 = idx4 - row * 48;
            v[i] = *(const float4*)(srcq + (size_t)row * 480 + 128 + col4 * 4);
        }
#pragma unroll
        for (int i = 0; i < 12; ++i) {
            const int idx4 = i * 64 + lane;
            const int row = idx4 / 48, col4 = idx4 - row * 48;
            const u16x4 w = { cvt1(v[i].x), cvt1(v[i].y), cvt1(v[i].z), cvt1(v[i].w) };
            *(u16x4*)&B[row * RR + col4 * 4] = w;
        }
    }
    f32x4 accP[3];
    {
        u16x8 f1[3][2];
#pragma unroll
        for (int kt = 0; kt < 2; ++kt) {
            const int base = lm * RR + 96 * kt + 24 * lg;
            const u16x8 sA = *(const u16x8*)&B[base];
            const u16x8 sB = *(const u16x8*)&B[base + 8];
            const u16x8 sC = *(const u16x8*)&B[base + 16];
            unsigned short span[24];
#pragma unroll
            for (int e = 0; e < 8; ++e) { span[e] = sA[e]; span[8+e] = sB[e]; span[16+e] = sC[e]; }
#pragma unroll
            for (int m = 0; m < 3; ++m) {
                u16x8 f;
#pragma unroll
                for (int j = 0; j < 8; ++j) f[j] = span[3 * j + m];
                f1[m][kt] = f;
            }
        }
#pragma unroll
        for (int m = 0; m < 3; ++m) {
            f32x4 acc = (f32x4){0.f,0.f,0.f,0.f};
#pragma unroll
            for (int kt = 0; kt < 2; ++kt)
                acc = MFMA16(f1[m][kt], *(const u16x8*)(wsS + 19456 + (size_t)(kt*64+lane)*8), acc);
            accP[m] = acc;
        }
    }

    // ================= phase l2: stage cols [320,480) =================
    {
        float4 v[10];
#pragma unroll
        for (int i = 0; i < 10; ++i) {
            const int idx4 = i * 64 + lane;
            const int row = idx4 / 40, col4 = idx4 - row * 40;
            v[i] = *(const float4*)(srcq + (size_t)row * 480 + 320 + col4 * 4);
        }
#pragma unroll
        for (int i = 0; i < 10; ++i) {
            const int idx4 = i * 64 + lane;
            const int row = idx4 / 40, col4 = idx4 - row * 40;
            const u16x4 w = { cvt1(v[i].x), cvt1(v[i].y), cvt1(v[i].z), cvt1(v[i].w) };
            *(u16x4*)&B[row * RR + col4 * 4] = w;
        }
    }
    f32x4 accQ[5];
    {
        unsigned short span[40];
        const int base = lm * RR + 40 * lg;
#pragma unroll
        for (int c = 0; c < 5; ++c) {
            const u16x8 s = *(const u16x8*)&B[base + c * 8];
#pragma unroll
            for (int e = 0; e < 8; ++e) span[c * 8 + e] = s[e];
        }
#pragma unroll
        for (int m = 0; m < 5; ++m) {
            u16x8 f;
#pragma unroll
            for (int j = 0; j < 8; ++j) f[j] = span[5 * j + m];
            accQ[m] = MFMA16(f, *(const u16x8*)(wsS + 20480 + (size_t)lane*8),
                             (f32x4){0.f,0.f,0.f,0.f});
        }
    }

    // ================= phase Xs: stage x_scalar =================
    {
        const float* __restrict__ src = x_scalar + (size_t)n0 * 128;
        float4 v[8];
#pragma unroll
        for (int i = 0; i < 8; ++i) {
            const int idx4 = i * 64 + lane;
            v[i] = *(const float4*)(src + (size_t)idx4 * 4);
        }
#pragma unroll
        for (int i = 0; i < 8; ++i) {
            const int idx4 = i * 64 + lane;
            const int row = idx4 >> 5, col4 = idx4 & 31;
            const u16x4 w = { cvt1(v[i].x), cvt1(v[i].y), cvt1(v[i].z), cvt1(v[i].w) };
            *(u16x4*)&B[row * RR + col4 * 4] = w;
        }
    }

    // ================= phase A: H = silu(Xs @ gw1 + gb1) =================
    f32x4 accA0, accA1, accA2, accA3;
    {
        const float b0 = gb1[lm], b1 = gb1[16 + lm], bv2 = gb1[32 + lm], b3 = gb1[48 + lm];
        accA0 = (f32x4){b0,b0,b0,b0}; accA1 = (f32x4){b1,b1,b1,b1};
        accA2 = (f32x4){bv2,bv2,bv2,bv2}; accA3 = (f32x4){b3,b3,b3,b3};
    }
#pragma unroll
    for (int kt = 0; kt < 4; ++kt) {
        const u16x8 af = *(const u16x8*)&B[lm * RR + kt * 32 + lg * 8];
        accA0 = MFMA16(af, *(const u16x8*)(wsS + (size_t)((0*4+kt)*64+lane)*8), accA0);
        accA1 = MFMA16(af, *(const u16x8*)(wsS + (size_t)((1*4+kt)*64+lane)*8), accA1);
        accA2 = MFMA16(af, *(const u16x8*)(wsS + (size_t)((2*4+kt)*64+lane)*8), accA2);
        accA3 = MFMA16(af, *(const u16x8*)(wsS + (size_t)((3*4+kt)*64+lane)*8), accA3);
    }
#pragma unroll
    for (int r = 0; r < 4; ++r) {   // silu -> sH (atom=lg*4+r, col=ct*16+lm)
        const int atom = lg * 4 + r;
        const float v0 = accA0[r], v1 = accA1[r], v2 = accA2[r], v3 = accA3[r];
        B[SHO + atom * 72 +  0 + lm] = cvt1(v0 / (1.f + __expf(-v0)));
        B[SHO + atom * 72 + 16 + lm] = cvt1(v1 / (1.f + __expf(-v1)));
        B[SHO + atom * 72 + 32 + lm] = cvt1(v2 / (1.f + __expf(-v2)));
        B[SHO + atom * 72 + 48 + lm] = cvt1(v3 / (1.f + __expf(-v3)));
    }

    // ================= phase B: G = b2p + H @ W2p =================
    const u16x8 hf0 = *(const u16x8*)&B[SHO + lm * 72 + lg * 8];
    const u16x8 hf1 = *(const u16x8*)&B[SHO + lm * 72 + 32 + lg * 8];
    f32x4 gB0, gB1, gB2, gB4, gB5, gB6, gB8;
#define INITB(ACC, CT) { const float b = b2p[(CT)*16 + lm]; ACC = (f32x4){b,b,b,b}; }
    INITB(gB0,0) INITB(gB1,1) INITB(gB2,2) INITB(gB4,4) INITB(gB5,5) INITB(gB6,6) INITB(gB8,8)
#define DOB(ACC, CT) \
    ACC = MFMA16(hf0, *(const u16x8*)(wsS + 8192 + (size_t)(((CT)*2+0)*64+lane)*8), ACC); \
    ACC = MFMA16(hf1, *(const u16x8*)(wsS + 8192 + (size_t)(((CT)*2+1)*64+lane)*8), ACC);
    DOB(gB0,0) DOB(gB1,1) DOB(gB2,2) DOB(gB4,4) DOB(gB5,5) DOB(gB6,6) DOB(gB8,8)

    // ================= TP epilogue =================
    const float C110 = 0.5773502691896258f;
    const float C220 = 0.4472135954999579f;
    const float Ca = 0.31622776601683794f, Cb = 0.18257418583505536f;
    const float A2 = 0.2390457218668787f, B2c = 0.20701966780270626f, D2 = 0.11952286093343936f;
    const float is3 = 0.5773502691896258f, is6 = 0.4082482904638631f, is2 = 0.7071067811865476f;

#pragma unroll
    for (int r = 0; r < 4; ++r) {
        const int row = lg * 4 + r;
        const float h0 = acc0[r];
        const float p0 = accP[0][r], p1 = accP[1][r], p2 = accP[2][r];
        const float q0 = accQ[0][r], q1 = accQ[1][r], q2 = accQ[2][r],
                    q3 = accQ[3][r], q4 = accQ[4][r];
        const float G0 = gB0[r], G1 = gB1[r], G2 = gB2[r], G4 = gB4[r],
                    G5 = gB5[r], G6 = gB6[r], G8 = gB8[r];

        float y0 = G0 * h0 * h0
                 + G2 * C110 * (p0*p0 + p1*p1 + p2*p2)
                 + G6 * C220 * (q0*q0 + q1*q1 + q2*q2 + q3*q3 + q4*q4);
        float z0, z1, z2, z3, z4;
        {
            const float c15 = C220 * h0 * (G1 + G5);
            z0 = c15 * q0; z1 = c15 * q1; z2 = c15 * q2; z3 = c15 * q3; z4 = c15 * q4;
        }
        z0 = fmaf(G4, 2.f*Ca*p0*p2, z0);
        z1 = fmaf(G4, 2.f*Ca*p0*p1, z1);
        z2 = fmaf(G4, Cb*(2.f*p1*p1 - p0*p0 - p2*p2), z2);
        z3 = fmaf(G4, 2.f*Ca*p2*p1, z3);
        z4 = fmaf(G4, Ca*(p2*p2 - p0*p0), z4);
        z0 = fmaf(G8, -2.f*A2*q0*q2 + 2.f*B2c*q1*q3, z0);
        z1 = fmaf(G8,  2.f*B2c*(q0*q3 - q4*q1) + 2.f*D2*q1*q2, z1);
        z2 = fmaf(G8,  A2*(q2*q2 - q0*q0 - q4*q4) + D2*(q1*q1 + q3*q3), z2);
        z3 = fmaf(G8,  2.f*B2c*(q0*q1 + q3*q4) + 2.f*D2*q2*q3, z3);
        z4 = fmaf(G8, -2.f*A2*q2*q4 + B2c*(q3*q3 - q1*q1), z4);

#pragma unroll
        for (int msk = 1; msk <= 8; msk <<= 1) {   // reduce over 16 u-lanes
            y0 += __shfl_xor(y0, msk, 64);
            z0 += __shfl_xor(z0, msk, 64);
            z1 += __shfl_xor(z1, msk, 64);
            z2 += __shfl_xor(z2, msk, 64);
            z3 += __shfl_xor(z3, msk, 64);
            z4 += __shfl_xor(z4, msk, 64);
        }

        const float c0 = y0*is3 - z2*is6 - z4*is2;
        const float c4 = y0*is3 + 2.f*z2*is6;
        const float c8 = y0*is3 - z2*is6 + z4*is2;
        const float c1 = z1*is2, c2v = z0*is2, c5 = z3*is2;
        if (lm < 9) {
            const float val = (lm==0)?c8 : (lm==1)?c2v : (lm==2)?c5 : (lm==3)?c2v
                            : (lm==4)?c0 : (lm==5)?c1 : (lm==6)?c5 : (lm==7)?c1 : c4;
            out[(size_t)(n0 + row) * 9 + lm] = val;
        }
    }
}

extern "C" void kernel_launch(void* const* d_in, const int* in_sizes, int n_in,
                              void* d_out, int out_size, void* d_ws, size_t ws_size,
                              hipStream_t stream) {
    const float* x_scalar = (const float*)d_in[0];
    const float* x_sph    = (const float*)d_in[1];
    const float* w_pre0   = (const float*)d_in[2];
    const float* w_pre1   = (const float*)d_in[3];
    const float* w_pre2   = (const float*)d_in[4];
    const float* gw1      = (const float*)d_in[5];
    const float* gb1      = (const float*)d_in[6];
    const float* gw2      = (const float*)d_in[7];
    const float* gb2      = (const float*)d_in[8];
    const float* wpost0   = (const float*)d_in[9];
    const float* wpost1   = (const float*)d_in[10];
    const float* wpost2   = (const float*)d_in[11];

    unsigned short* wsS = (unsigned short*)d_ws;
    float* b2p = (float*)((char*)d_ws + 41984);

    setup_kernel<<<83, 256, 0, stream>>>(gw1, gw2, gb2, w_pre0, w_pre1, w_pre2,
                                         wpost0, wpost1, wpost2, wsS, b2p);
    csc_kernel<<<NA / 64, 256, 0, stream>>>(x_scalar, x_sph, gb1, wsS, b2p, (float*)d_out);
}